// Round 2
// baseline (179.565 us; speedup 1.0000x reference)
//
#include <hip/hip_runtime.h>
#include <hip/hip_bf16.h>

// ---------------------------------------------------------------------------
// SingleHead attention: q=xWq, k=xWk, v=xWv; causal softmax(qk^T/sqrt(64)) v
// B=8, T=2048, C=1024, D=64.  Output fp32 [B,T,64].
//
//   k0: WT bf16 transpose of [Wq|Wk|Wv] (192x1024), 0.125 folded into q
//   k1: barrier-free QKV projection (MFMA 16x16x32 bf16), WT read from L2
//   k2: split-K flash attention partials (chunked KV) -> (o, m, l)
//   k3: combine partials (max/exp weighting) -> out
// ---------------------------------------------------------------------------

typedef __attribute__((ext_vector_type(8))) short short8;   // 8 x bf16 frag
typedef __attribute__((ext_vector_type(4))) float f32x4;    // C/D frag
typedef __attribute__((ext_vector_type(4))) unsigned int u32x4;

#define MFMA16(a, b, c) __builtin_amdgcn_mfma_f32_16x16x32_bf16((a), (b), (c), 0, 0, 0)

__device__ __forceinline__ unsigned short f2bf(float f) {
  unsigned int u = __builtin_bit_cast(unsigned int, f);
  unsigned int r = 0x7fffu + ((u >> 16) & 1u);
  return (unsigned short)((u + r) >> 16);
}

#define BATCH 8
#define SEQ   2048
#define CDIM  1024
#define DDIM  64
#define NTOK  (BATCH * SEQ)   // 16384
#define LOG2E 1.44269504f

// ---------------------------------------------------------------------------
// Kernel 0: WT[c'][k] = W_{c'/64}[k][c'%64]  (bf16), q cols scaled by 0.125
// ---------------------------------------------------------------------------
__global__ __launch_bounds__(256) void wt_kernel(const float* __restrict__ Wq,
                                                 const float* __restrict__ Wk,
                                                 const float* __restrict__ Wv,
                                                 unsigned short* __restrict__ WT) {
  int tid = blockIdx.x * 256 + threadIdx.x;       // 0 .. 196607
  int c    = tid & 63;
  int rest = tid >> 6;
  int k    = rest & 1023;
  int wi   = rest >> 10;                          // 0,1,2
  const float* W = (wi == 0) ? Wq : ((wi == 1) ? Wk : Wv);
  float v = W[k * DDIM + c];
  if (wi == 0) v *= 0.125f;
  WT[(size_t)(wi * 64 + c) * CDIM + k] = f2bf(v);
}

// ---------------------------------------------------------------------------
// Kernel 1: fused QKV projection, barrier-free (WT straight from L2).
//   Block: 128 thr = 2 waves, 32 tokens/block; wave: 16 tokens x 192 feats.
// ---------------------------------------------------------------------------
__global__ __launch_bounds__(128) void proj_kernel(const float* __restrict__ x,
                                                   const unsigned short* __restrict__ WT,
                                                   unsigned short* __restrict__ qws,
                                                   unsigned short* __restrict__ kws,
                                                   unsigned short* __restrict__ vtws) {
  const int tid  = threadIdx.x;
  const int lane = tid & 63;
  const int w    = tid >> 6;
  const int c16  = lane & 15;      // token lane (B col / D col)
  const int hi   = lane >> 4;      // k-group
  const int token = blockIdx.x * 32 + w * 16 + c16;

  f32x4 acc[12];
#pragma unroll
  for (int i = 0; i < 12; ++i) acc[i] = (f32x4){0.f, 0.f, 0.f, 0.f};

  const float* xrow = x + (size_t)token * CDIM;

  for (int k0 = 0; k0 < CDIM; k0 += 32) {
    // B fragment: x[token][k0 + hi*8 .. +7], fp32 -> bf16
    float xf[8];
    *reinterpret_cast<f32x4*>(&xf[0]) = *reinterpret_cast<const f32x4*>(xrow + k0 + hi * 8);
    *reinterpret_cast<f32x4*>(&xf[4]) = *reinterpret_cast<const f32x4*>(xrow + k0 + hi * 8 + 4);
    short8 bx;
#pragma unroll
    for (int j = 0; j < 8; ++j) bx[j] = (short)f2bf(xf[j]);

#pragma unroll
    for (int ct = 0; ct < 12; ++ct) {
      short8 a = *reinterpret_cast<const short8*>(
          WT + (size_t)(ct * 16 + c16) * CDIM + k0 + hi * 8);
      acc[ct] = MFMA16(a, bx, acc[ct]);
    }
  }

  // Epilogue: lane holds D[feat = ct*16 + hi*4 + r][token]
  const int b = token >> 11;
  const int t = token & 2047;
#pragma unroll
  for (int ct = 0; ct < 12; ++ct) {
    int cg = ct * 16 + hi * 4;
    unsigned short h[4];
#pragma unroll
    for (int r = 0; r < 4; ++r) h[r] = f2bf(acc[ct][r]);
    if (cg < 64) {
      ushort4 h4 = make_ushort4(h[0], h[1], h[2], h[3]);
      *reinterpret_cast<ushort4*>(qws + (size_t)token * DDIM + cg) = h4;
    } else if (cg < 128) {
      ushort4 h4 = make_ushort4(h[0], h[1], h[2], h[3]);
      *reinterpret_cast<ushort4*>(kws + (size_t)token * DDIM + (cg - 64)) = h4;
    } else {
      int cv = cg - 128;
#pragma unroll
      for (int r = 0; r < 4; ++r)
        vtws[(size_t)(b * DDIM + cv + r) * SEQ + t] = h[r];
    }
  }
}

// ---------------------------------------------------------------------------
// Kernel 2: split-K flash attention partials.
//   Grid (32 qtiles, MAXCH chunks, B); 256 thr = 4 waves; wave = 16 q rows.
//   Writes unnormalized o + per-row (m, l) to workspace.
// ---------------------------------------------------------------------------
__global__ __launch_bounds__(256) void attn_partial(const unsigned short* __restrict__ qws,
                                                    const unsigned short* __restrict__ kws,
                                                    const unsigned short* __restrict__ vtws,
                                                    float* __restrict__ po,
                                                    float* __restrict__ pml,
                                                    int MAXCH, int CHUNK) {
  __shared__ unsigned short plds[4][16 * 72];

  const int qt = blockIdx.x;
  const int ch = blockIdx.y;
  const int b  = blockIdx.z;

  const int kv_end  = qt * 64 + 64;          // exclusive, block level
  const int kv0_ch  = ch * CHUNK;
  if (kv0_ch >= kv_end) return;              // inactive chunk
  const int chunk_hi = min(kv0_ch + CHUNK, kv_end);

  const int tid  = threadIdx.x;
  const int lane = tid & 63;
  const int w    = tid >> 6;
  const int c    = lane & 15;
  const int hi   = lane >> 4;
  const int qr0  = qt * 64 + w * 16;

  const unsigned short* qb = qws + (size_t)b * SEQ * DDIM;
  const unsigned short* kb = kws + (size_t)b * SEQ * DDIM;
  const unsigned short* vb = vtws + (size_t)b * DDIM * SEQ;

  short8 aq0 = *reinterpret_cast<const short8*>(qb + (size_t)(qr0 + c) * DDIM + hi * 8);
  short8 aq1 = *reinterpret_cast<const short8*>(qb + (size_t)(qr0 + c) * DDIM + 32 + hi * 8);

  float m[4], lsum[4];
  f32x4 o[4];
#pragma unroll
  for (int r = 0; r < 4; ++r) { m[r] = -INFINITY; lsum[r] = 0.f; }
#pragma unroll
  for (int dn = 0; dn < 4; ++dn) o[dn] = (f32x4){0.f, 0.f, 0.f, 0.f};

  unsigned short* pw = plds[w];

  const int kv_last = qr0 + 15;                       // causal limit for wave
  const int lim     = min(chunk_hi, kv_last + 1);

  for (int kv0 = kv0_ch; kv0 < lim; kv0 += 64) {
    // ---- S = q k^T ----
    f32x4 s[4];
#pragma unroll
    for (int n = 0; n < 4; ++n) {
      int col0 = kv0 + n * 16;
      if (col0 > kv_last) {
        s[n] = (f32x4){-INFINITY, -INFINITY, -INFINITY, -INFINITY};
        continue;
      }
      const unsigned short* krow = kb + (size_t)(col0 + c) * DDIM;
      short8 bk0 = *reinterpret_cast<const short8*>(krow + hi * 8);
      short8 bk1 = *reinterpret_cast<const short8*>(krow + 32 + hi * 8);
      f32x4 z = (f32x4){0.f, 0.f, 0.f, 0.f};
      z = MFMA16(aq0, bk0, z);
      s[n] = MFMA16(aq1, bk1, z);
    }

    // ---- causal mask near diagonal ----
    if (kv0 + 63 > qr0) {
#pragma unroll
      for (int n = 0; n < 4; ++n) {
        int col = kv0 + n * 16 + c;
#pragma unroll
        for (int r = 0; r < 4; ++r) {
          int row = qr0 + hi * 4 + r;
          if (col > row) s[n][r] = -INFINITY;
        }
      }
    }

    // ---- online softmax ----
    float p[4][4];
    float oscale[4];
#pragma unroll
    for (int r = 0; r < 4; ++r) {
      float mx = fmaxf(fmaxf(s[0][r], s[1][r]), fmaxf(s[2][r], s[3][r]));
#pragma unroll
      for (int off = 1; off < 16; off <<= 1) mx = fmaxf(mx, __shfl_xor(mx, off, 64));
      float nm = fmaxf(m[r], mx);
      float sc = __builtin_exp2f((m[r] - nm) * LOG2E);
      m[r] = nm;
      float ssum = 0.f;
#pragma unroll
      for (int n = 0; n < 4; ++n) {
        float pv = __builtin_exp2f((s[n][r] - nm) * LOG2E);
        p[n][r] = pv;
        ssum += pv;
      }
#pragma unroll
      for (int off = 1; off < 16; off <<= 1) ssum += __shfl_xor(ssum, off, 64);
      lsum[r] = lsum[r] * sc + ssum;
      oscale[r] = sc;
    }
#pragma unroll
    for (int dn = 0; dn < 4; ++dn)
#pragma unroll
      for (int r = 0; r < 4; ++r) o[dn][r] *= oscale[r];

    // ---- P -> LDS (bf16) ----
#pragma unroll
    for (int n = 0; n < 4; ++n)
#pragma unroll
      for (int r = 0; r < 4; ++r)
        pw[(hi * 4 + r) * 72 + n * 16 + c] = f2bf(p[n][r]);

    // ---- PV ----
#pragma unroll
    for (int f = 0; f < 2; ++f) {
      short8 pa = *reinterpret_cast<const short8*>(&pw[c * 72 + f * 32 + hi * 8]);
#pragma unroll
      for (int dn = 0; dn < 4; ++dn) {
        short8 bv = *reinterpret_cast<const short8*>(
            vb + (size_t)(dn * 16 + c) * SEQ + kv0 + f * 32 + hi * 8);
        o[dn] = MFMA16(pa, bv, o[dn]);
      }
    }
  }

  // ---- write partials ----
  float* pob = po + (((size_t)(b * 32 + qt) * MAXCH + ch) * 64 + w * 16) * 64;
#pragma unroll
  for (int dn = 0; dn < 4; ++dn)
#pragma unroll
    for (int r = 0; r < 4; ++r)
      pob[(hi * 4 + r) * 64 + dn * 16 + c] = o[dn][r];

  if (c == 0) {
    float* pmb = pml + (((size_t)(b * 32 + qt) * MAXCH + ch) * 64 + w * 16) * 2;
#pragma unroll
    for (int r = 0; r < 4; ++r) {
      pmb[(hi * 4 + r) * 2]     = m[r];
      pmb[(hi * 4 + r) * 2 + 1] = lsum[r];
    }
  }
}

// ---------------------------------------------------------------------------
// Kernel 3: combine partials.  Grid (32, B), 256 thr; thread = 1 row x 16 col
// ---------------------------------------------------------------------------
__global__ __launch_bounds__(256) void attn_combine(const float* __restrict__ po,
                                                    const float* __restrict__ pml,
                                                    float* __restrict__ out,
                                                    int MAXCH, int CHUNK) {
  const int qt = blockIdx.x;
  const int b  = blockIdx.y;
  const int tid = threadIdx.x;
  const int row = tid >> 2;
  const int cg  = tid & 3;
  const int nch = (qt * 64 + 64 + CHUNK - 1) / CHUNK;

  const size_t base = (size_t)(b * 32 + qt) * MAXCH;

  float M = -INFINITY;
  for (int ch = 0; ch < nch; ++ch)
    M = fmaxf(M, pml[(base + ch) * 128 + row * 2]);

  float L = 0.f;
  f32x4 a0 = {0.f,0.f,0.f,0.f}, a1 = a0, a2 = a0, a3 = a0;
  for (int ch = 0; ch < nch; ++ch) {
    float mv = pml[(base + ch) * 128 + row * 2];
    float lv = pml[(base + ch) * 128 + row * 2 + 1];
    float wgt = __builtin_exp2f((mv - M) * LOG2E);
    L += wgt * lv;
    const float* p = po + (base + ch) * 4096 + row * 64 + cg * 16;
    a0 += wgt * *reinterpret_cast<const f32x4*>(p);
    a1 += wgt * *reinterpret_cast<const f32x4*>(p + 4);
    a2 += wgt * *reinterpret_cast<const f32x4*>(p + 8);
    a3 += wgt * *reinterpret_cast<const f32x4*>(p + 12);
  }
  float invL = 1.f / L;
  float* ob = out + ((size_t)b * SEQ + qt * 64 + row) * 64 + cg * 16;
  *reinterpret_cast<f32x4*>(ob)      = a0 * invL;
  *reinterpret_cast<f32x4*>(ob + 4)  = a1 * invL;
  *reinterpret_cast<f32x4*>(ob + 8)  = a2 * invL;
  *reinterpret_cast<f32x4*>(ob + 12) = a3 * invL;
}

// ---------------------------------------------------------------------------
// Fallback: direct causal flash attention (used when ws too small for splitK)
// ---------------------------------------------------------------------------
__global__ __launch_bounds__(256) void attn_kernel(const unsigned short* __restrict__ qws,
                                                   const unsigned short* __restrict__ kws,
                                                   const unsigned short* __restrict__ vtws,
                                                   float* __restrict__ out) {
  __shared__ unsigned short plds[4][16 * 72];

  const int bq   = blockIdx.x;
  const int b    = blockIdx.y;
  const int tid  = threadIdx.x;
  const int lane = tid & 63;
  const int w    = tid >> 6;
  const int c    = lane & 15;
  const int hi   = lane >> 4;
  const int qr0  = bq * 64 + w * 16;

  const unsigned short* qb = qws + (size_t)b * SEQ * DDIM;
  const unsigned short* kb = kws + (size_t)b * SEQ * DDIM;
  const unsigned short* vb = vtws + (size_t)b * DDIM * SEQ;

  short8 aq0 = *reinterpret_cast<const short8*>(qb + (size_t)(qr0 + c) * DDIM + hi * 8);
  short8 aq1 = *reinterpret_cast<const short8*>(qb + (size_t)(qr0 + c) * DDIM + 32 + hi * 8);

  float m[4], lsum[4];
  f32x4 o[4];
#pragma unroll
  for (int r = 0; r < 4; ++r) { m[r] = -INFINITY; lsum[r] = 0.f; }
#pragma unroll
  for (int dn = 0; dn < 4; ++dn) o[dn] = (f32x4){0.f, 0.f, 0.f, 0.f};

  unsigned short* pw = plds[w];
  const int kv_last = qr0 + 15;
  const int ntiles  = (kv_last + 64) >> 6;

  for (int it = 0; it < ntiles; ++it) {
    const int kv0 = it * 64;
    f32x4 s[4];
#pragma unroll
    for (int n = 0; n < 4; ++n) {
      int col0 = kv0 + n * 16;
      if (col0 > kv_last) {
        s[n] = (f32x4){-INFINITY, -INFINITY, -INFINITY, -INFINITY};
        continue;
      }
      const unsigned short* krow = kb + (size_t)(col0 + c) * DDIM;
      short8 bk0 = *reinterpret_cast<const short8*>(krow + hi * 8);
      short8 bk1 = *reinterpret_cast<const short8*>(krow + 32 + hi * 8);
      f32x4 z = (f32x4){0.f, 0.f, 0.f, 0.f};
      z = MFMA16(aq0, bk0, z);
      s[n] = MFMA16(aq1, bk1, z);
    }
    if (kv0 + 63 > qr0) {
#pragma unroll
      for (int n = 0; n < 4; ++n) {
        int col = kv0 + n * 16 + c;
#pragma unroll
        for (int r = 0; r < 4; ++r) {
          int row = qr0 + hi * 4 + r;
          if (col > row) s[n][r] = -INFINITY;
        }
      }
    }
    float p[4][4], oscale[4];
#pragma unroll
    for (int r = 0; r < 4; ++r) {
      float mx = fmaxf(fmaxf(s[0][r], s[1][r]), fmaxf(s[2][r], s[3][r]));
#pragma unroll
      for (int off = 1; off < 16; off <<= 1) mx = fmaxf(mx, __shfl_xor(mx, off, 64));
      float nm = fmaxf(m[r], mx);
      float sc = __builtin_exp2f((m[r] - nm) * LOG2E);
      m[r] = nm;
      float ssum = 0.f;
#pragma unroll
      for (int n = 0; n < 4; ++n) {
        float pv = __builtin_exp2f((s[n][r] - nm) * LOG2E);
        p[n][r] = pv;
        ssum += pv;
      }
#pragma unroll
      for (int off = 1; off < 16; off <<= 1) ssum += __shfl_xor(ssum, off, 64);
      lsum[r] = lsum[r] * sc + ssum;
      oscale[r] = sc;
    }
#pragma unroll
    for (int dn = 0; dn < 4; ++dn)
#pragma unroll
      for (int r = 0; r < 4; ++r) o[dn][r] *= oscale[r];
#pragma unroll
    for (int n = 0; n < 4; ++n)
#pragma unroll
      for (int r = 0; r < 4; ++r)
        pw[(hi * 4 + r) * 72 + n * 16 + c] = f2bf(p[n][r]);
#pragma unroll
    for (int f = 0; f < 2; ++f) {
      short8 pa = *reinterpret_cast<const short8*>(&pw[c * 72 + f * 32 + hi * 8]);
#pragma unroll
      for (int dn = 0; dn < 4; ++dn) {
        short8 bv = *reinterpret_cast<const short8*>(
            vb + (size_t)(dn * 16 + c) * SEQ + kv0 + f * 32 + hi * 8);
        o[dn] = MFMA16(pa, bv, o[dn]);
      }
    }
  }

  float inv[4];
#pragma unroll
  for (int r = 0; r < 4; ++r) inv[r] = 1.f / lsum[r];
  float* ob = out + ((size_t)b * SEQ + qr0) * DDIM;
#pragma unroll
  for (int dn = 0; dn < 4; ++dn)
#pragma unroll
    for (int r = 0; r < 4; ++r)
      ob[(hi * 4 + r) * DDIM + dn * 16 + c] = o[dn][r] * inv[r];
}

// ---------------------------------------------------------------------------
extern "C" void kernel_launch(void* const* d_in, const int* in_sizes, int n_in,
                              void* d_out, int out_size, void* d_ws, size_t ws_size,
                              hipStream_t stream) {
  const float* x  = (const float*)d_in[0];
  const float* Wq = (const float*)d_in[1];
  const float* Wk = (const float*)d_in[2];
  const float* Wv = (const float*)d_in[3];
  float* out = (float*)d_out;

  unsigned short* qws  = (unsigned short*)d_ws;            // 2MB
  unsigned short* kws  = qws + (size_t)NTOK * DDIM;        // 2MB
  unsigned short* vtws = kws + (size_t)NTOK * DDIM;        // 2MB
  unsigned short* WT   = vtws + (size_t)NTOK * DDIM;       // 384KB
  size_t fixed_end = (size_t)NTOK * DDIM * 3 * 2 + 192 * 1024 * 2;

  // choose split-K factor from available workspace
  int MAXCH = 0;
  {
    const int cand[4] = {8, 4, 2, 1};
    for (int i = 0; i < 4; ++i) {
      size_t need = fixed_end +
                    (size_t)cand[i] * (8ull * 32 * 64 * 64 * 4 + 8ull * 32 * 64 * 2 * 4);
      if (need <= ws_size) { MAXCH = cand[i]; break; }
    }
  }

  wt_kernel<<<768, 256, 0, stream>>>(Wq, Wk, Wv, WT);
  proj_kernel<<<NTOK / 32, 128, 0, stream>>>(x, WT, qws, kws, vtws);

  if (MAXCH > 0) {
    float* po  = (float*)((char*)d_ws + fixed_end);
    float* pml = po + (size_t)BATCH * 32 * MAXCH * 64 * 64;
    int CHUNK = SEQ / MAXCH;
    attn_partial<<<dim3(32, MAXCH, BATCH), 256, 0, stream>>>(qws, kws, vtws, po, pml,
                                                             MAXCH, CHUNK);
    attn_combine<<<dim3(32, BATCH), 256, 0, stream>>>(po, pml, out, MAXCH, CHUNK);
  } else {
    attn_kernel<<<dim3(SEQ / 64, BATCH), 256, 0, stream>>>(qws, kws, vtws, out);
  }
}

// Round 3
// 102.211 us; speedup vs baseline: 1.7568x; 1.7568x over previous
//
#include <hip/hip_runtime.h>
#include <hip/hip_bf16.h>

// ---------------------------------------------------------------------------
// SingleHead attention: q=xWq, k=xWk, v=xWv; causal softmax(qk^T/sqrt(64)) v
// B=8, T=2048, C=1024, D=64.  Output fp32 [B,T,64].
//
//   k0: WT bf16 transpose of [Wq|Wk|Wv] (192x1024), pre-swizzled tile layout
//       (16 tiles of [192][64], XOR-swizzled 16B chunks), 0.125 folded into q
//   k1: QKV projection GEMM, 64 tok x 192 ft block, K-step 64, dbuf LDS,
//       WT via global_load_lds (linear dest = swizzled image), x reg-staged
//   k2: split-K flash attention partials (chunked KV) -> (o, m, l)
//   k3: combine partials
// ---------------------------------------------------------------------------

typedef __attribute__((ext_vector_type(8))) short short8;   // 8 x bf16 frag
typedef __attribute__((ext_vector_type(4))) float f32x4;    // C/D frag

#define MFMA16(a, b, c) __builtin_amdgcn_mfma_f32_16x16x32_bf16((a), (b), (c), 0, 0, 0)

__device__ __forceinline__ unsigned short f2bf(float f) {
  unsigned int u = __builtin_bit_cast(unsigned int, f);
  unsigned int r = 0x7fffu + ((u >> 16) & 1u);
  return (unsigned short)((u + r) >> 16);
}

#define BATCH 8
#define SEQ   2048
#define CDIM  1024
#define DDIM  64
#define NTOK  (BATCH * SEQ)   // 16384
#define LOG2E 1.44269504f

// ---------------------------------------------------------------------------
// Kernel 0: WT pre-swizzled tiles.
//   tile = k>>6 (16 tiles), row = wi*64 + c (192), col = k&63.
//   element offset in tile = row*64 + ((col>>3) ^ (row&7))*8 + (col&7)
// ---------------------------------------------------------------------------
__global__ __launch_bounds__(256) void wt_kernel(const float* __restrict__ Wq,
                                                 const float* __restrict__ Wk,
                                                 const float* __restrict__ Wv,
                                                 unsigned short* __restrict__ WT) {
  int tid = blockIdx.x * 256 + threadIdx.x;       // 0 .. 196607
  int c    = tid & 63;
  int rest = tid >> 6;
  int k    = rest & 1023;
  int wi   = rest >> 10;                          // 0,1,2
  const float* W = (wi == 0) ? Wq : ((wi == 1) ? Wk : Wv);
  float v = W[k * DDIM + c];                      // coalesced read
  if (wi == 0) v *= 0.125f;
  int row  = wi * 64 + c;
  int step = k >> 6;
  int col  = k & 63;
  size_t idx = (size_t)step * 12288 + (size_t)row * 64 +
               (size_t)(((col >> 3) ^ (row & 7)) * 8) + (col & 7);
  WT[idx] = f2bf(v);
}

// ---------------------------------------------------------------------------
// Kernel 1: fused QKV projection GEMM.
//   512 thr = 8 waves (2M x 4N). Block tile 64 tok x 192 ft. K-step 64.
//   Wave tile: 32 tok (2 sub) x 48 ft (3 ct). 12 MFMA / wave / K-step.
// ---------------------------------------------------------------------------
__global__ __launch_bounds__(512) void proj_kernel(const float* __restrict__ x,
                                                   const unsigned short* __restrict__ WT,
                                                   unsigned short* __restrict__ qws,
                                                   unsigned short* __restrict__ kws,
                                                   unsigned short* __restrict__ vtws) {
  __shared__ __align__(16) unsigned short xs[2][64 * 64];    // 8KB each
  __shared__ __align__(16) unsigned short wl[2][192 * 64];   // 24KB each

  const int tid  = threadIdx.x;
  const int lane = tid & 63;
  const int w    = tid >> 6;       // 0..7
  const int wm   = w & 1;          // M half
  const int wn   = w >> 1;         // N quarter
  const int c16  = lane & 15;
  const int hi   = lane >> 4;
  const int n0   = blockIdx.x * 64;
  const int trow = tid >> 3;       // 0..63 (x staging row)
  const int kch  = tid & 7;        // 0..7  (x staging 16B chunk)

  f32x4 acc[2][3];
#pragma unroll
  for (int ts = 0; ts < 2; ++ts)
#pragma unroll
    for (int ct = 0; ct < 3; ++ct) acc[ts][ct] = (f32x4){0.f, 0.f, 0.f, 0.f};

  const float* xbase = x + (size_t)(n0 + trow) * CDIM + kch * 8;
  const int xsw = trow * 64 + ((kch ^ (trow & 7)) * 8);   // swizzled x slot

  // WT staging: 3 x 1KB chunks per wave per step, linear global->LDS
  const unsigned short* wsrc = WT + (size_t)w * 1536 + (size_t)lane * 8;
  auto stage_wt = [&](int step, int bufi) {
    const unsigned short* s = wsrc + (size_t)step * 12288;
    unsigned short* d = &wl[bufi][w * 1536];
#pragma unroll
    for (int j = 0; j < 3; ++j)
      __builtin_amdgcn_global_load_lds(
          (const __attribute__((address_space(1))) void*)(s + j * 512),
          (__attribute__((address_space(3))) void*)(d + j * 512), 16, 0, 0);
  };

  // ---- prologue: step 0 ----
  f32x4 xa = *reinterpret_cast<const f32x4*>(xbase);
  f32x4 xb = *reinterpret_cast<const f32x4*>(xbase + 4);
  stage_wt(0, 0);
  {
    short8 h;
#pragma unroll
    for (int j = 0; j < 4; ++j) { h[j] = (short)f2bf(xa[j]); h[4 + j] = (short)f2bf(xb[j]); }
    *reinterpret_cast<short8*>(&xs[0][xsw]) = h;
  }
  __syncthreads();

  int cur = 0;
  for (int st = 0; st < 16; ++st) {
    if (st < 15) {
      xa = *reinterpret_cast<const f32x4*>(xbase + (st + 1) * 64);
      xb = *reinterpret_cast<const f32x4*>(xbase + (st + 1) * 64 + 4);
      stage_wt(st + 1, cur ^ 1);
    }

    // ---- compute on cur ----
    short8 bfrag[2][2];
#pragma unroll
    for (int ts = 0; ts < 2; ++ts) {
      int r = wm * 32 + ts * 16 + c16;
#pragma unroll
      for (int f = 0; f < 2; ++f)
        bfrag[ts][f] = *reinterpret_cast<const short8*>(
            &xs[cur][r * 64 + (((f * 4 + hi) ^ (r & 7)) * 8)]);
    }
#pragma unroll
    for (int ct = 0; ct < 3; ++ct) {
      int ra = (wn * 3 + ct) * 16 + c16;
#pragma unroll
      for (int f = 0; f < 2; ++f) {
        short8 af = *reinterpret_cast<const short8*>(
            &wl[cur][ra * 64 + (((f * 4 + hi) ^ (ra & 7)) * 8)]);
#pragma unroll
        for (int ts = 0; ts < 2; ++ts)
          acc[ts][ct] = MFMA16(af, bfrag[ts][f], acc[ts][ct]);
      }
    }

    if (st < 15) {
      short8 h;
#pragma unroll
      for (int j = 0; j < 4; ++j) { h[j] = (short)f2bf(xa[j]); h[4 + j] = (short)f2bf(xb[j]); }
      *reinterpret_cast<short8*>(&xs[cur ^ 1][xsw]) = h;
    }
    __syncthreads();
    cur ^= 1;
  }

  // ---- epilogue: lane holds D[feat = ctg*16+hi*4+r][token] ----
#pragma unroll
  for (int ts = 0; ts < 2; ++ts) {
    const int token = n0 + wm * 32 + ts * 16 + c16;
    const int b = token >> 11;
    const int t = token & 2047;
#pragma unroll
    for (int ct = 0; ct < 3; ++ct) {
      int cg = (wn * 3 + ct) * 16 + hi * 4;
      unsigned short h[4];
#pragma unroll
      for (int r = 0; r < 4; ++r) h[r] = f2bf(acc[ts][ct][r]);
      if (cg < 64) {
        *reinterpret_cast<ushort4*>(qws + (size_t)token * DDIM + cg) =
            make_ushort4(h[0], h[1], h[2], h[3]);
      } else if (cg < 128) {
        *reinterpret_cast<ushort4*>(kws + (size_t)token * DDIM + (cg - 64)) =
            make_ushort4(h[0], h[1], h[2], h[3]);
      } else {
        int cv = cg - 128;
#pragma unroll
        for (int r = 0; r < 4; ++r)
          vtws[(size_t)(b * DDIM + cv + r) * SEQ + t] = h[r];
      }
    }
  }
}

// ---------------------------------------------------------------------------
// Kernel 2: split-K flash attention partials.
// ---------------------------------------------------------------------------
__global__ __launch_bounds__(256) void attn_partial(const unsigned short* __restrict__ qws,
                                                    const unsigned short* __restrict__ kws,
                                                    const unsigned short* __restrict__ vtws,
                                                    float* __restrict__ po,
                                                    float* __restrict__ pml,
                                                    int MAXCH, int CHUNK) {
  __shared__ unsigned short plds[4][16 * 72];

  const int qt = blockIdx.x;
  const int ch = blockIdx.y;
  const int b  = blockIdx.z;

  const int kv_end  = qt * 64 + 64;
  const int kv0_ch  = ch * CHUNK;
  if (kv0_ch >= kv_end) return;
  const int chunk_hi = min(kv0_ch + CHUNK, kv_end);

  const int tid  = threadIdx.x;
  const int lane = tid & 63;
  const int w    = tid >> 6;
  const int c    = lane & 15;
  const int hi   = lane >> 4;
  const int qr0  = qt * 64 + w * 16;

  const unsigned short* qb = qws + (size_t)b * SEQ * DDIM;
  const unsigned short* kb = kws + (size_t)b * SEQ * DDIM;
  const unsigned short* vb = vtws + (size_t)b * DDIM * SEQ;

  short8 aq0 = *reinterpret_cast<const short8*>(qb + (size_t)(qr0 + c) * DDIM + hi * 8);
  short8 aq1 = *reinterpret_cast<const short8*>(qb + (size_t)(qr0 + c) * DDIM + 32 + hi * 8);

  float m[4], lsum[4];
  f32x4 o[4];
#pragma unroll
  for (int r = 0; r < 4; ++r) { m[r] = -INFINITY; lsum[r] = 0.f; }
#pragma unroll
  for (int dn = 0; dn < 4; ++dn) o[dn] = (f32x4){0.f, 0.f, 0.f, 0.f};

  unsigned short* pw = plds[w];
  const int kv_last = qr0 + 15;
  const int lim     = min(chunk_hi, kv_last + 1);

  for (int kv0 = kv0_ch; kv0 < lim; kv0 += 64) {
    f32x4 s[4];
#pragma unroll
    for (int n = 0; n < 4; ++n) {
      int col0 = kv0 + n * 16;
      if (col0 > kv_last) {
        s[n] = (f32x4){-INFINITY, -INFINITY, -INFINITY, -INFINITY};
        continue;
      }
      const unsigned short* krow = kb + (size_t)(col0 + c) * DDIM;
      short8 bk0 = *reinterpret_cast<const short8*>(krow + hi * 8);
      short8 bk1 = *reinterpret_cast<const short8*>(krow + 32 + hi * 8);
      f32x4 z = (f32x4){0.f, 0.f, 0.f, 0.f};
      z = MFMA16(aq0, bk0, z);
      s[n] = MFMA16(aq1, bk1, z);
    }

    if (kv0 + 63 > qr0) {
#pragma unroll
      for (int n = 0; n < 4; ++n) {
        int col = kv0 + n * 16 + c;
#pragma unroll
        for (int r = 0; r < 4; ++r) {
          int row = qr0 + hi * 4 + r;
          if (col > row) s[n][r] = -INFINITY;
        }
      }
    }

    float p[4][4], oscale[4];
#pragma unroll
    for (int r = 0; r < 4; ++r) {
      float mx = fmaxf(fmaxf(s[0][r], s[1][r]), fmaxf(s[2][r], s[3][r]));
#pragma unroll
      for (int off = 1; off < 16; off <<= 1) mx = fmaxf(mx, __shfl_xor(mx, off, 64));
      float nm = fmaxf(m[r], mx);
      float sc = __builtin_exp2f((m[r] - nm) * LOG2E);
      m[r] = nm;
      float ssum = 0.f;
#pragma unroll
      for (int n = 0; n < 4; ++n) {
        float pv = __builtin_exp2f((s[n][r] - nm) * LOG2E);
        p[n][r] = pv;
        ssum += pv;
      }
#pragma unroll
      for (int off = 1; off < 16; off <<= 1) ssum += __shfl_xor(ssum, off, 64);
      lsum[r] = lsum[r] * sc + ssum;
      oscale[r] = sc;
    }
#pragma unroll
    for (int dn = 0; dn < 4; ++dn)
#pragma unroll
      for (int r = 0; r < 4; ++r) o[dn][r] *= oscale[r];

#pragma unroll
    for (int n = 0; n < 4; ++n)
#pragma unroll
      for (int r = 0; r < 4; ++r)
        pw[(hi * 4 + r) * 72 + n * 16 + c] = f2bf(p[n][r]);

#pragma unroll
    for (int f = 0; f < 2; ++f) {
      short8 pa = *reinterpret_cast<const short8*>(&pw[c * 72 + f * 32 + hi * 8]);
#pragma unroll
      for (int dn = 0; dn < 4; ++dn) {
        short8 bv = *reinterpret_cast<const short8*>(
            vb + (size_t)(dn * 16 + c) * SEQ + kv0 + f * 32 + hi * 8);
        o[dn] = MFMA16(pa, bv, o[dn]);
      }
    }
  }

  float* pob = po + (((size_t)(b * 32 + qt) * MAXCH + ch) * 64 + w * 16) * 64;
#pragma unroll
  for (int dn = 0; dn < 4; ++dn)
#pragma unroll
    for (int r = 0; r < 4; ++r)
      pob[(hi * 4 + r) * 64 + dn * 16 + c] = o[dn][r];

  if (c == 0) {
    float* pmb = pml + (((size_t)(b * 32 + qt) * MAXCH + ch) * 64 + w * 16) * 2;
#pragma unroll
    for (int r = 0; r < 4; ++r) {
      pmb[(hi * 4 + r) * 2]     = m[r];
      pmb[(hi * 4 + r) * 2 + 1] = lsum[r];
    }
  }
}

// ---------------------------------------------------------------------------
// Kernel 3: combine partials.
// ---------------------------------------------------------------------------
__global__ __launch_bounds__(256) void attn_combine(const float* __restrict__ po,
                                                    const float* __restrict__ pml,
                                                    float* __restrict__ out,
                                                    int MAXCH, int CHUNK) {
  const int qt = blockIdx.x;
  const int b  = blockIdx.y;
  const int tid = threadIdx.x;
  const int row = tid >> 2;
  const int cg  = tid & 3;
  const int nch = (qt * 64 + 64 + CHUNK - 1) / CHUNK;

  const size_t base = (size_t)(b * 32 + qt) * MAXCH;

  float M = -INFINITY;
  for (int ch = 0; ch < nch; ++ch)
    M = fmaxf(M, pml[(base + ch) * 128 + row * 2]);

  float L = 0.f;
  f32x4 a0 = {0.f,0.f,0.f,0.f}, a1 = a0, a2 = a0, a3 = a0;
  for (int ch = 0; ch < nch; ++ch) {
    float mv = pml[(base + ch) * 128 + row * 2];
    float lv = pml[(base + ch) * 128 + row * 2 + 1];
    float wgt = __builtin_exp2f((mv - M) * LOG2E);
    L += wgt * lv;
    const float* p = po + (base + ch) * 4096 + row * 64 + cg * 16;
    a0 += wgt * *reinterpret_cast<const f32x4*>(p);
    a1 += wgt * *reinterpret_cast<const f32x4*>(p + 4);
    a2 += wgt * *reinterpret_cast<const f32x4*>(p + 8);
    a3 += wgt * *reinterpret_cast<const f32x4*>(p + 12);
  }
  float invL = 1.f / L;
  float* ob = out + ((size_t)b * SEQ + qt * 64 + row) * 64 + cg * 16;
  *reinterpret_cast<f32x4*>(ob)      = a0 * invL;
  *reinterpret_cast<f32x4*>(ob + 4)  = a1 * invL;
  *reinterpret_cast<f32x4*>(ob + 8)  = a2 * invL;
  *reinterpret_cast<f32x4*>(ob + 12) = a3 * invL;
}

// ---------------------------------------------------------------------------
// Fallback: direct causal flash attention (ws too small for split-K)
// ---------------------------------------------------------------------------
__global__ __launch_bounds__(256) void attn_kernel(const unsigned short* __restrict__ qws,
                                                   const unsigned short* __restrict__ kws,
                                                   const unsigned short* __restrict__ vtws,
                                                   float* __restrict__ out) {
  __shared__ unsigned short plds[4][16 * 72];

  const int bq   = blockIdx.x;
  const int b    = blockIdx.y;
  const int tid  = threadIdx.x;
  const int lane = tid & 63;
  const int w    = tid >> 6;
  const int c    = lane & 15;
  const int hi   = lane >> 4;
  const int qr0  = bq * 64 + w * 16;

  const unsigned short* qb = qws + (size_t)b * SEQ * DDIM;
  const unsigned short* kb = kws + (size_t)b * SEQ * DDIM;
  const unsigned short* vb = vtws + (size_t)b * DDIM * SEQ;

  short8 aq0 = *reinterpret_cast<const short8*>(qb + (size_t)(qr0 + c) * DDIM + hi * 8);
  short8 aq1 = *reinterpret_cast<const short8*>(qb + (size_t)(qr0 + c) * DDIM + 32 + hi * 8);

  float m[4], lsum[4];
  f32x4 o[4];
#pragma unroll
  for (int r = 0; r < 4; ++r) { m[r] = -INFINITY; lsum[r] = 0.f; }
#pragma unroll
  for (int dn = 0; dn < 4; ++dn) o[dn] = (f32x4){0.f, 0.f, 0.f, 0.f};

  unsigned short* pw = plds[w];
  const int kv_last = qr0 + 15;
  const int ntiles  = (kv_last + 64) >> 6;

  for (int it = 0; it < ntiles; ++it) {
    const int kv0 = it * 64;
    f32x4 s[4];
#pragma unroll
    for (int n = 0; n < 4; ++n) {
      int col0 = kv0 + n * 16;
      if (col0 > kv_last) {
        s[n] = (f32x4){-INFINITY, -INFINITY, -INFINITY, -INFINITY};
        continue;
      }
      const unsigned short* krow = kb + (size_t)(col0 + c) * DDIM;
      short8 bk0 = *reinterpret_cast<const short8*>(krow + hi * 8);
      short8 bk1 = *reinterpret_cast<const short8*>(krow + 32 + hi * 8);
      f32x4 z = (f32x4){0.f, 0.f, 0.f, 0.f};
      z = MFMA16(aq0, bk0, z);
      s[n] = MFMA16(aq1, bk1, z);
    }
    if (kv0 + 63 > qr0) {
#pragma unroll
      for (int n = 0; n < 4; ++n) {
        int col = kv0 + n * 16 + c;
#pragma unroll
        for (int r = 0; r < 4; ++r) {
          int row = qr0 + hi * 4 + r;
          if (col > row) s[n][r] = -INFINITY;
        }
      }
    }
    float p[4][4], oscale[4];
#pragma unroll
    for (int r = 0; r < 4; ++r) {
      float mx = fmaxf(fmaxf(s[0][r], s[1][r]), fmaxf(s[2][r], s[3][r]));
#pragma unroll
      for (int off = 1; off < 16; off <<= 1) mx = fmaxf(mx, __shfl_xor(mx, off, 64));
      float nm = fmaxf(m[r], mx);
      float sc = __builtin_exp2f((m[r] - nm) * LOG2E);
      m[r] = nm;
      float ssum = 0.f;
#pragma unroll
      for (int n = 0; n < 4; ++n) {
        float pv = __builtin_exp2f((s[n][r] - nm) * LOG2E);
        p[n][r] = pv;
        ssum += pv;
      }
#pragma unroll
      for (int off = 1; off < 16; off <<= 1) ssum += __shfl_xor(ssum, off, 64);
      lsum[r] = lsum[r] * sc + ssum;
      oscale[r] = sc;
    }
#pragma unroll
    for (int dn = 0; dn < 4; ++dn)
#pragma unroll
      for (int r = 0; r < 4; ++r) o[dn][r] *= oscale[r];
#pragma unroll
    for (int n = 0; n < 4; ++n)
#pragma unroll
      for (int r = 0; r < 4; ++r)
        pw[(hi * 4 + r) * 72 + n * 16 + c] = f2bf(p[n][r]);
#pragma unroll
    for (int f = 0; f < 2; ++f) {
      short8 pa = *reinterpret_cast<const short8*>(&pw[c * 72 + f * 32 + hi * 8]);
#pragma unroll
      for (int dn = 0; dn < 4; ++dn) {
        short8 bv = *reinterpret_cast<const short8*>(
            vb + (size_t)(dn * 16 + c) * SEQ + kv0 + f * 32 + hi * 8);
        o[dn] = MFMA16(pa, bv, o[dn]);
      }
    }
  }

  float inv[4];
#pragma unroll
  for (int r = 0; r < 4; ++r) inv[r] = 1.f / lsum[r];
  float* ob = out + ((size_t)b * SEQ + qr0) * DDIM;
#pragma unroll
  for (int dn = 0; dn < 4; ++dn)
#pragma unroll
    for (int r = 0; r < 4; ++r)
      ob[(hi * 4 + r) * DDIM + dn * 16 + c] = o[dn][r] * inv[r];
}

// ---------------------------------------------------------------------------
extern "C" void kernel_launch(void* const* d_in, const int* in_sizes, int n_in,
                              void* d_out, int out_size, void* d_ws, size_t ws_size,
                              hipStream_t stream) {
  const float* x  = (const float*)d_in[0];
  const float* Wq = (const float*)d_in[1];
  const float* Wk = (const float*)d_in[2];
  const float* Wv = (const float*)d_in[3];
  float* out = (float*)d_out;

  unsigned short* qws  = (unsigned short*)d_ws;            // 2MB
  unsigned short* kws  = qws + (size_t)NTOK * DDIM;        // 2MB
  unsigned short* vtws = kws + (size_t)NTOK * DDIM;        // 2MB
  unsigned short* WT   = vtws + (size_t)NTOK * DDIM;       // 384KB
  size_t fixed_end = (size_t)NTOK * DDIM * 3 * 2 + 192 * 1024 * 2;

  int MAXCH = 0;
  {
    const int cand[4] = {8, 4, 2, 1};
    for (int i = 0; i < 4; ++i) {
      size_t need = fixed_end +
                    (size_t)cand[i] * (8ull * 32 * 64 * 64 * 4 + 8ull * 32 * 64 * 2 * 4);
      if (need <= ws_size) { MAXCH = cand[i]; break; }
    }
  }

  wt_kernel<<<768, 256, 0, stream>>>(Wq, Wk, Wv, WT);
  proj_kernel<<<NTOK / 64, 512, 0, stream>>>(x, WT, qws, kws, vtws);

  if (MAXCH > 0) {
    float* po  = (float*)((char*)d_ws + fixed_end);
    float* pml = po + (size_t)BATCH * 32 * MAXCH * 64 * 64;
    int CHUNK = SEQ / MAXCH;
    attn_partial<<<dim3(32, MAXCH, BATCH), 256, 0, stream>>>(qws, kws, vtws, po, pml,
                                                             MAXCH, CHUNK);
    attn_combine<<<dim3(32, BATCH), 256, 0, stream>>>(po, pml, out, MAXCH, CHUNK);
  } else {
    attn_kernel<<<dim3(SEQ / 64, BATCH), 256, 0, stream>>>(qws, kws, vtws, out);
  }
}

// Round 4
// 66.992 us; speedup vs baseline: 2.6804x; 1.5257x over previous
//
#include <hip/hip_runtime.h>
#include <hip/hip_bf16.h>

// ---------------------------------------------------------------------------
// SingleHead attention: q=xWq, k=xWk, v=xWv; causal softmax(qk^T/sqrt(64)) v
// B=8, T=2048, C=1024, D=64.  Output fp32 [B,T,64].
//
//   k0: WT bf16 transpose of [Wq|Wk|Wv] (192x1024), pre-swizzled tile layout,
//       0.125*log2(e) folded into q columns (softmax runs in exp2 domain)
//   k1: QKV projection GEMM (64 tok x 192 ft block, K-step 64, dbuf LDS,
//       WT via global_load_lds; x reg-staged)
//   k2: split-K flash attention partials, swapped-QK^T (S^T = K Q^T) so the
//       softmax reduction axis is lane-local; K/V staged in LDS (xor-swizzled
//       via pre-swizzled global source addresses); O^T = V^T P^T keeps m/l
//       state lane-local.  -> (o, m, l) partials
//   k3: combine partials
// ---------------------------------------------------------------------------

typedef __attribute__((ext_vector_type(8))) short short8;   // 8 x bf16 frag
typedef __attribute__((ext_vector_type(4))) float f32x4;    // C/D frag
typedef __attribute__((ext_vector_type(4))) unsigned int u32x4;

#define MFMA16(a, b, c) __builtin_amdgcn_mfma_f32_16x16x32_bf16((a), (b), (c), 0, 0, 0)

__device__ __forceinline__ unsigned short f2bf(float f) {
  unsigned int u = __builtin_bit_cast(unsigned int, f);
  unsigned int r = 0x7fffu + ((u >> 16) & 1u);
  return (unsigned short)((u + r) >> 16);
}

#define BATCH 8
#define SEQ   2048
#define CDIM  1024
#define DDIM  64
#define NTOK  (BATCH * SEQ)   // 16384
#define LOG2E 1.44269504f

// ---------------------------------------------------------------------------
// Kernel 0: WT pre-swizzled tiles (for proj's global_load_lds staging).
//   tile = k>>6 (16 tiles of [192][64]), row = wi*64+c, col = k&63
//   offset in tile = row*64 + ((col>>3) ^ (row&7))*8 + (col&7)
// ---------------------------------------------------------------------------
__global__ __launch_bounds__(256) void wt_kernel(const float* __restrict__ Wq,
                                                 const float* __restrict__ Wk,
                                                 const float* __restrict__ Wv,
                                                 unsigned short* __restrict__ WT) {
  int tid = blockIdx.x * 256 + threadIdx.x;       // 0 .. 196607
  int c    = tid & 63;
  int rest = tid >> 6;
  int k    = rest & 1023;
  int wi   = rest >> 10;                          // 0,1,2
  const float* W = (wi == 0) ? Wq : ((wi == 1) ? Wk : Wv);
  float v = W[k * DDIM + c];                      // coalesced read
  if (wi == 0) v *= 0.125f * LOG2E;               // fold scale + log2e into q
  int row  = wi * 64 + c;
  int step = k >> 6;
  int col  = k & 63;
  size_t idx = (size_t)step * 12288 + (size_t)row * 64 +
               (size_t)(((col >> 3) ^ (row & 7)) * 8) + (col & 7);
  WT[idx] = f2bf(v);
}

// ---------------------------------------------------------------------------
// Kernel 1: fused QKV projection GEMM.
//   512 thr = 8 waves (2M x 4N). Block tile 64 tok x 192 ft. K-step 64.
// ---------------------------------------------------------------------------
__global__ __launch_bounds__(512) void proj_kernel(const float* __restrict__ x,
                                                   const unsigned short* __restrict__ WT,
                                                   unsigned short* __restrict__ qws,
                                                   unsigned short* __restrict__ kws,
                                                   unsigned short* __restrict__ vtws) {
  __shared__ __align__(16) unsigned short xs[2][64 * 64];    // 8KB each
  __shared__ __align__(16) unsigned short wl[2][192 * 64];   // 24KB each

  const int tid  = threadIdx.x;
  const int lane = tid & 63;
  const int w    = tid >> 6;       // 0..7
  const int wm   = w & 1;          // M half
  const int wn   = w >> 1;         // N quarter
  const int c16  = lane & 15;
  const int hi   = lane >> 4;
  const int n0   = blockIdx.x * 64;
  const int trow = tid >> 3;       // 0..63 (x staging row)
  const int kch  = tid & 7;        // 0..7  (x staging 16B chunk)

  f32x4 acc[2][3];
#pragma unroll
  for (int ts = 0; ts < 2; ++ts)
#pragma unroll
    for (int ct = 0; ct < 3; ++ct) acc[ts][ct] = (f32x4){0.f, 0.f, 0.f, 0.f};

  const float* xbase = x + (size_t)(n0 + trow) * CDIM + kch * 8;
  const int xsw = trow * 64 + ((kch ^ (trow & 7)) * 8);   // swizzled x slot

  const unsigned short* wsrc = WT + (size_t)w * 1536 + (size_t)lane * 8;
  auto stage_wt = [&](int step, int bufi) {
    const unsigned short* s = wsrc + (size_t)step * 12288;
    unsigned short* d = &wl[bufi][w * 1536];
#pragma unroll
    for (int j = 0; j < 3; ++j)
      __builtin_amdgcn_global_load_lds(
          (const __attribute__((address_space(1))) void*)(s + j * 512),
          (__attribute__((address_space(3))) void*)(d + j * 512), 16, 0, 0);
  };

  // ---- prologue: step 0 ----
  f32x4 xa = *reinterpret_cast<const f32x4*>(xbase);
  f32x4 xb = *reinterpret_cast<const f32x4*>(xbase + 4);
  stage_wt(0, 0);
  {
    short8 h;
#pragma unroll
    for (int j = 0; j < 4; ++j) { h[j] = (short)f2bf(xa[j]); h[4 + j] = (short)f2bf(xb[j]); }
    *reinterpret_cast<short8*>(&xs[0][xsw]) = h;
  }
  __syncthreads();

  int cur = 0;
  for (int st = 0; st < 16; ++st) {
    if (st < 15) {
      xa = *reinterpret_cast<const f32x4*>(xbase + (st + 1) * 64);
      xb = *reinterpret_cast<const f32x4*>(xbase + (st + 1) * 64 + 4);
      stage_wt(st + 1, cur ^ 1);
    }

    short8 bfrag[2][2];
#pragma unroll
    for (int ts = 0; ts < 2; ++ts) {
      int r = wm * 32 + ts * 16 + c16;
#pragma unroll
      for (int f = 0; f < 2; ++f)
        bfrag[ts][f] = *reinterpret_cast<const short8*>(
            &xs[cur][r * 64 + (((f * 4 + hi) ^ (r & 7)) * 8)]);
    }
#pragma unroll
    for (int ct = 0; ct < 3; ++ct) {
      int ra = (wn * 3 + ct) * 16 + c16;
#pragma unroll
      for (int f = 0; f < 2; ++f) {
        short8 af = *reinterpret_cast<const short8*>(
            &wl[cur][ra * 64 + (((f * 4 + hi) ^ (ra & 7)) * 8)]);
#pragma unroll
        for (int ts = 0; ts < 2; ++ts)
          acc[ts][ct] = MFMA16(af, bfrag[ts][f], acc[ts][ct]);
      }
    }

    if (st < 15) {
      short8 h;
#pragma unroll
      for (int j = 0; j < 4; ++j) { h[j] = (short)f2bf(xa[j]); h[4 + j] = (short)f2bf(xb[j]); }
      *reinterpret_cast<short8*>(&xs[cur ^ 1][xsw]) = h;
    }
    __syncthreads();
    cur ^= 1;
  }

  // ---- epilogue ----
#pragma unroll
  for (int ts = 0; ts < 2; ++ts) {
    const int token = n0 + wm * 32 + ts * 16 + c16;
    const int b = token >> 11;
    const int t = token & 2047;
#pragma unroll
    for (int ct = 0; ct < 3; ++ct) {
      int cg = (wn * 3 + ct) * 16 + hi * 4;
      unsigned short h[4];
#pragma unroll
      for (int r = 0; r < 4; ++r) h[r] = f2bf(acc[ts][ct][r]);
      if (cg < 64) {
        *reinterpret_cast<ushort4*>(qws + (size_t)token * DDIM + cg) =
            make_ushort4(h[0], h[1], h[2], h[3]);
      } else if (cg < 128) {
        *reinterpret_cast<ushort4*>(kws + (size_t)token * DDIM + (cg - 64)) =
            make_ushort4(h[0], h[1], h[2], h[3]);
      } else {
        int cv = cg - 128;
#pragma unroll
        for (int r = 0; r < 4; ++r)
          vtws[(size_t)(b * DDIM + cv + r) * SEQ + t] = h[r];
      }
    }
  }
}

// ---------------------------------------------------------------------------
// Kernel 2: split-K flash attention partials, swapped-QK^T.
//   Grid (32 qtiles, MAXCH chunks, B); 256 thr = 4 waves; wave = 16 q rows.
//   Lane owns q = qr0 + (lane&15); m/l state lane-local.
//   K tile + V^T tile staged in LDS (xor chunk swizzle via src address).
// ---------------------------------------------------------------------------
__global__ __launch_bounds__(256) void attn_partial(const unsigned short* __restrict__ qws,
                                                    const unsigned short* __restrict__ kws,
                                                    const unsigned short* __restrict__ vtws,
                                                    float* __restrict__ po,
                                                    float* __restrict__ pml,
                                                    int MAXCH, int CHUNK) {
  __shared__ __align__(16) unsigned short kt[64 * 64];   // K tile  [kv][d]
  __shared__ __align__(16) unsigned short vt[64 * 64];   // V^T tile [dv][kv]
  __shared__ unsigned short pt[4][64 * 26];              // P^T per wave [kv][q]

  const int qt = blockIdx.x;
  const int ch = blockIdx.y;
  const int b  = blockIdx.z;

  const int kv_end = qt * 64 + 64;
  const int kv0_ch = ch * CHUNK;
  if (kv0_ch >= kv_end) return;
  const int block_lim = min(kv0_ch + CHUNK, kv_end);

  const int tid  = threadIdx.x;
  const int lane = tid & 63;
  const int w    = tid >> 6;
  const int c    = lane & 15;
  const int hi   = lane >> 4;
  const int qr0  = qt * 64 + w * 16;
  const int q    = qr0 + c;            // this lane's q row
  const int kv_last = qr0 + 15;        // wave causal limit

  const unsigned short* qb = qws + (size_t)b * SEQ * DDIM;
  short8 aq0 = *reinterpret_cast<const short8*>(qb + (size_t)q * DDIM + hi * 8);
  short8 aq1 = *reinterpret_cast<const short8*>(qb + (size_t)q * DDIM + 32 + hi * 8);

  float m = -INFINITY, l = 0.f;
  f32x4 o[4];
#pragma unroll
  for (int dn = 0; dn < 4; ++dn) o[dn] = (f32x4){0.f, 0.f, 0.f, 0.f};

  unsigned short* pw = pt[w];
  const unsigned short* kb = kws + (size_t)b * SEQ * DDIM;
  const unsigned short* vb = vtws + (size_t)b * DDIM * SEQ;

  for (int kv0 = kv0_ch; kv0 < block_lim; kv0 += 64) {
    __syncthreads();
    // ---- stage K tile and V^T tile (xor-swizzled source, linear LDS) ----
#pragma unroll
    for (int j = 0; j < 2; ++j) {
      int p   = w * 128 + j * 64 + lane;   // 16B chunk index 0..511
      int row = p >> 3;
      int chk = (p & 7) ^ (row & 7);
      __builtin_amdgcn_global_load_lds(
          (const __attribute__((address_space(1))) void*)(kb + (size_t)(kv0 + row) * DDIM + chk * 8),
          (__attribute__((address_space(3))) void*)(kt + w * 1024 + j * 512), 16, 0, 0);
      __builtin_amdgcn_global_load_lds(
          (const __attribute__((address_space(1))) void*)(vb + (size_t)row * SEQ + kv0 + chk * 8),
          (__attribute__((address_space(3))) void*)(vt + w * 1024 + j * 512), 16, 0, 0);
    }
    asm volatile("s_waitcnt vmcnt(0)" ::: "memory");
    __syncthreads();

    if (kv0 > kv_last) continue;     // wave-uniform; barriers stay aligned

    // ---- S^T = K q^T : lane holds S^T[kv = n*16+hi*4+r][q=c] ----
    f32x4 s[4];
#pragma unroll
    for (int n = 0; n < 4; ++n) {
      if (kv0 + n * 16 > kv_last) {
        s[n] = (f32x4){-INFINITY, -INFINITY, -INFINITY, -INFINITY};
        continue;
      }
      const unsigned short* kr = kt + (n * 16 + c) * 64;
      short8 ka0 = *reinterpret_cast<const short8*>(kr + ((hi ^ (c & 7)) * 8));
      short8 ka1 = *reinterpret_cast<const short8*>(kr + (((4 + hi) ^ (c & 7)) * 8));
      f32x4 z = (f32x4){0.f, 0.f, 0.f, 0.f};
      z = MFMA16(ka0, aq0, z);
      s[n] = MFMA16(ka1, aq1, z);
    }

    // ---- causal mask (near diagonal only) ----
    if (kv0 + 63 > qr0) {
#pragma unroll
      for (int n = 0; n < 4; ++n)
#pragma unroll
        for (int r = 0; r < 4; ++r)
          if (kv0 + n * 16 + hi * 4 + r > q) s[n][r] = -INFINITY;
    }

    // ---- online softmax (exp2 domain; state lane-local) ----
    float mx = -INFINITY;
#pragma unroll
    for (int n = 0; n < 4; ++n)
      mx = fmaxf(mx, fmaxf(fmaxf(s[n][0], s[n][1]), fmaxf(s[n][2], s[n][3])));
    mx = fmaxf(mx, __shfl_xor(mx, 16, 64));
    mx = fmaxf(mx, __shfl_xor(mx, 32, 64));

    float nm = fmaxf(m, mx);
    float sc = __builtin_exp2f(m - nm);
    m = nm;

    float ssum = 0.f;
#pragma unroll
    for (int n = 0; n < 4; ++n)
#pragma unroll
      for (int r = 0; r < 4; ++r) {
        float pv = __builtin_exp2f(s[n][r] - nm);
        pw[(n * 16 + hi * 4 + r) * 26 + c] = f2bf(pv);
        ssum += pv;
      }
    ssum += __shfl_xor(ssum, 16, 64);
    ssum += __shfl_xor(ssum, 32, 64);
    l = l * sc + ssum;

#pragma unroll
    for (int dn = 0; dn < 4; ++dn) o[dn] *= sc;

    // ---- O^T += V^T P^T ----
    const int nf = (kv0 + 32 <= kv_last) ? 2 : 1;
    for (int f = 0; f < nf; ++f) {
      short8 bp;
#pragma unroll
      for (int j = 0; j < 8; ++j)
        bp[j] = (short)pw[(f * 32 + hi * 8 + j) * 26 + c];
#pragma unroll
      for (int dn = 0; dn < 4; ++dn) {
        const unsigned short* vr = vt + (dn * 16 + c) * 64;
        short8 va = *reinterpret_cast<const short8*>(vr + (((f * 4 + hi) ^ (c & 7)) * 8));
        o[dn] = MFMA16(va, bp, o[dn]);
      }
    }
  }

  // ---- write partials: po [q-in-tile][dv], lane holds dv=dn*16+hi*4+r ----
  float* pob = po + (((size_t)(b * 32 + qt) * MAXCH + ch) * 64 + w * 16 + c) * 64 + hi * 4;
#pragma unroll
  for (int dn = 0; dn < 4; ++dn)
    *reinterpret_cast<f32x4*>(pob + dn * 16) = o[dn];

  if (hi == 0) {
    *reinterpret_cast<float2*>(
        pml + (((size_t)(b * 32 + qt) * MAXCH + ch) * 64 + w * 16 + c) * 2) =
        make_float2(m, l);
  }
}

// ---------------------------------------------------------------------------
// Kernel 3: combine partials.  Grid (32, B), 256 thr; thread = 1 row x 16 col
// ---------------------------------------------------------------------------
__global__ __launch_bounds__(256) void attn_combine(const float* __restrict__ po,
                                                    const float* __restrict__ pml,
                                                    float* __restrict__ out,
                                                    int MAXCH, int CHUNK) {
  const int qt = blockIdx.x;
  const int b  = blockIdx.y;
  const int tid = threadIdx.x;
  const int row = tid >> 2;
  const int cg  = tid & 3;
  const int nch = (qt * 64 + 64 + CHUNK - 1) / CHUNK;

  const size_t base = (size_t)(b * 32 + qt) * MAXCH;

  float M = -INFINITY;
  for (int ch = 0; ch < nch; ++ch)
    M = fmaxf(M, pml[(base + ch) * 128 + row * 2]);

  float L = 0.f;
  f32x4 a0 = {0.f,0.f,0.f,0.f}, a1 = a0, a2 = a0, a3 = a0;
  for (int ch = 0; ch < nch; ++ch) {
    float mv = pml[(base + ch) * 128 + row * 2];
    float lv = pml[(base + ch) * 128 + row * 2 + 1];
    float wgt = __builtin_exp2f(mv - M);
    L += wgt * lv;
    const float* p = po + (base + ch) * 4096 + row * 64 + cg * 16;
    a0 += wgt * *reinterpret_cast<const f32x4*>(p);
    a1 += wgt * *reinterpret_cast<const f32x4*>(p + 4);
    a2 += wgt * *reinterpret_cast<const f32x4*>(p + 8);
    a3 += wgt * *reinterpret_cast<const f32x4*>(p + 12);
  }
  float invL = 1.f / L;
  float* ob = out + ((size_t)b * SEQ + qt * 64 + row) * 64 + cg * 16;
  *reinterpret_cast<f32x4*>(ob)      = a0 * invL;
  *reinterpret_cast<f32x4*>(ob + 4)  = a1 * invL;
  *reinterpret_cast<f32x4*>(ob + 8)  = a2 * invL;
  *reinterpret_cast<f32x4*>(ob + 12) = a3 * invL;
}

// ---------------------------------------------------------------------------
extern "C" void kernel_launch(void* const* d_in, const int* in_sizes, int n_in,
                              void* d_out, int out_size, void* d_ws, size_t ws_size,
                              hipStream_t stream) {
  const float* x  = (const float*)d_in[0];
  const float* Wq = (const float*)d_in[1];
  const float* Wk = (const float*)d_in[2];
  const float* Wv = (const float*)d_in[3];
  float* out = (float*)d_out;

  unsigned short* qws  = (unsigned short*)d_ws;            // 2MB
  unsigned short* kws  = qws + (size_t)NTOK * DDIM;        // 2MB
  unsigned short* vtws = kws + (size_t)NTOK * DDIM;        // 2MB
  unsigned short* WT   = vtws + (size_t)NTOK * DDIM;       // 384KB
  size_t fixed_end = (size_t)NTOK * DDIM * 3 * 2 + 192 * 1024 * 2;

  int MAXCH = 1;
  {
    const int cand[4] = {8, 4, 2, 1};
    for (int i = 0; i < 4; ++i) {
      size_t need = fixed_end +
                    (size_t)cand[i] * (8ull * 32 * 64 * 64 * 4 + 8ull * 32 * 64 * 2 * 4);
      if (need <= ws_size) { MAXCH = cand[i]; break; }
    }
  }

  wt_kernel<<<768, 256, 0, stream>>>(Wq, Wk, Wv, WT);
  proj_kernel<<<NTOK / 64, 512, 0, stream>>>(x, WT, qws, kws, vtws);

  float* po  = (float*)((char*)d_ws + fixed_end);
  float* pml = po + (size_t)BATCH * 32 * MAXCH * 64 * 64;
  int CHUNK = SEQ / MAXCH;
  attn_partial<<<dim3(32, MAXCH, BATCH), 256, 0, stream>>>(qws, kws, vtws, po, pml,
                                                           MAXCH, CHUNK);
  attn_combine<<<dim3(32, BATCH), 256, 0, stream>>>(po, pml, out, MAXCH, CHUNK);
}

// Round 5
// 65.797 us; speedup vs baseline: 2.7291x; 1.0182x over previous
//
#include <hip/hip_runtime.h>
#include <hip/hip_bf16.h>

// ---------------------------------------------------------------------------
// SingleHead attention: q=xWq, k=xWk, v=xWv; causal softmax(qk^T/sqrt(64)) v
// B=8, T=2048, C=1024, D=64.  Output fp32 [B,T,64].
//
//   k0: WT bf16 transpose of [Wq|Wk|Wv] (192x1024), pre-swizzled tile layout,
//       0.125*log2(e) folded into q columns (softmax runs in exp2 domain)
//   k1: QKV projection GEMM, 32 tok x 192 ft block (512 blocks = 2/CU),
//       K-step 64, dbuf LDS, x reg-prefetch depth 2, WT via global_load_lds
//   k2: split-K flash attention partials, swapped-QK^T, K/V LDS double-buffer
//   k3: combine partials
// ---------------------------------------------------------------------------

typedef __attribute__((ext_vector_type(8))) short short8;   // 8 x bf16 frag
typedef __attribute__((ext_vector_type(4))) float f32x4;    // C/D frag

#define MFMA16(a, b, c) __builtin_amdgcn_mfma_f32_16x16x32_bf16((a), (b), (c), 0, 0, 0)

__device__ __forceinline__ unsigned short f2bf(float f) {
  unsigned int u = __builtin_bit_cast(unsigned int, f);
  unsigned int r = 0x7fffu + ((u >> 16) & 1u);
  return (unsigned short)((u + r) >> 16);
}

#define BATCH 8
#define SEQ   2048
#define CDIM  1024
#define DDIM  64
#define NTOK  (BATCH * SEQ)   // 16384
#define LOG2E 1.44269504f

// ---------------------------------------------------------------------------
// Kernel 0: WT pre-swizzled tiles (for proj's global_load_lds staging).
//   tile = k>>6 (16 tiles of [192][64]), row = wi*64+c, col = k&63
//   offset in tile = row*64 + ((col>>3) ^ (row&7))*8 + (col&7)
// ---------------------------------------------------------------------------
__global__ __launch_bounds__(256) void wt_kernel(const float* __restrict__ Wq,
                                                 const float* __restrict__ Wk,
                                                 const float* __restrict__ Wv,
                                                 unsigned short* __restrict__ WT) {
  int tid = blockIdx.x * 256 + threadIdx.x;       // 0 .. 196607
  int c    = tid & 63;
  int rest = tid >> 6;
  int k    = rest & 1023;
  int wi   = rest >> 10;                          // 0,1,2
  const float* W = (wi == 0) ? Wq : ((wi == 1) ? Wk : Wv);
  float v = W[k * DDIM + c];                      // coalesced read
  if (wi == 0) v *= 0.125f * LOG2E;               // fold scale + log2e into q
  int row  = wi * 64 + c;
  int step = k >> 6;
  int col  = k & 63;
  size_t idx = (size_t)step * 12288 + (size_t)row * 64 +
               (size_t)(((col >> 3) ^ (row & 7)) * 8) + (col & 7);
  WT[idx] = f2bf(v);
}

// ---------------------------------------------------------------------------
// Kernel 1: fused QKV projection GEMM.
//   512 thr = 8 waves (2M x 4N). Block tile 32 tok x 192 ft. K-step 64.
//   x register-prefetched 2 steps ahead; WT LDS-dbuf via global_load_lds.
// ---------------------------------------------------------------------------
__global__ __launch_bounds__(512) void proj_kernel(const float* __restrict__ x,
                                                   const unsigned short* __restrict__ WT,
                                                   unsigned short* __restrict__ qws,
                                                   unsigned short* __restrict__ kws,
                                                   unsigned short* __restrict__ vtws) {
  __shared__ __align__(16) unsigned short xs[2][32 * 64];    // 4KB each
  __shared__ __align__(16) unsigned short wl[2][192 * 64];   // 24KB each

  const int tid  = threadIdx.x;
  const int lane = tid & 63;
  const int w    = tid >> 6;       // 0..7
  const int wm   = w & 1;          // M half (16 tok)
  const int wn   = w >> 1;         // N quarter (48 ft)
  const int c16  = lane & 15;
  const int hi   = lane >> 4;
  const int n0   = blockIdx.x * 32;
  const bool xldr = (tid < 256);
  const int trow = (tid >> 3) & 31;  // 0..31 (x staging row, tid<256)
  const int kch  = tid & 7;          // 0..7  (x staging 16B chunk)

  f32x4 acc[3];
#pragma unroll
  for (int ct = 0; ct < 3; ++ct) acc[ct] = (f32x4){0.f, 0.f, 0.f, 0.f};

  const float* xbase = x + (size_t)(n0 + trow) * CDIM + kch * 8;
  const int xsw = trow * 64 + ((kch ^ (trow & 7)) * 8);   // swizzled x slot

  const unsigned short* wsrc = WT + (size_t)w * 1536 + (size_t)lane * 8;
  auto stage_wt = [&](int step, int bufi) {
    const unsigned short* s = wsrc + (size_t)step * 12288;
    unsigned short* d = &wl[bufi][w * 1536];
#pragma unroll
    for (int j = 0; j < 3; ++j)
      __builtin_amdgcn_global_load_lds(
          (const __attribute__((address_space(1))) void*)(s + j * 512),
          (__attribute__((address_space(3))) void*)(d + j * 512), 16, 0, 0);
  };
  auto xstore = [&](f32x4 a, f32x4 b, int bufi) {
    short8 h;
#pragma unroll
    for (int j = 0; j < 4; ++j) { h[j] = (short)f2bf(a[j]); h[4 + j] = (short)f2bf(b[j]); }
    *reinterpret_cast<short8*>(&xs[bufi][xsw]) = h;
  };

  // ---- prologue ----
  f32x4 xa1 = {0,0,0,0}, xb1 = xa1, xa2 = xa1, xb2 = xa1;
  if (xldr) {
    f32x4 a0 = *reinterpret_cast<const f32x4*>(xbase);
    f32x4 b0 = *reinterpret_cast<const f32x4*>(xbase + 4);
    xstore(a0, b0, 0);
    xa1 = *reinterpret_cast<const f32x4*>(xbase + 64);
    xb1 = *reinterpret_cast<const f32x4*>(xbase + 64 + 4);
  }
  stage_wt(0, 0);
  __syncthreads();

  int cur = 0;
  for (int st = 0; st < 16; ++st) {
    if (st + 2 < 16 && xldr) {
      xa2 = *reinterpret_cast<const f32x4*>(xbase + (st + 2) * 64);
      xb2 = *reinterpret_cast<const f32x4*>(xbase + (st + 2) * 64 + 4);
    }
    if (st + 1 < 16) stage_wt(st + 1, cur ^ 1);

    // ---- compute on cur ----
    short8 bfrag[2];
    {
      int r = wm * 16 + c16;
#pragma unroll
      for (int f = 0; f < 2; ++f)
        bfrag[f] = *reinterpret_cast<const short8*>(
            &xs[cur][r * 64 + (((f * 4 + hi) ^ (r & 7)) * 8)]);
    }
#pragma unroll
    for (int ct = 0; ct < 3; ++ct) {
      int ra = (wn * 3 + ct) * 16 + c16;
#pragma unroll
      for (int f = 0; f < 2; ++f) {
        short8 af = *reinterpret_cast<const short8*>(
            &wl[cur][ra * 64 + (((f * 4 + hi) ^ (ra & 7)) * 8)]);
        acc[ct] = MFMA16(af, bfrag[f], acc[ct]);
      }
    }

    if (st + 1 < 16 && xldr) xstore(xa1, xb1, cur ^ 1);
    __syncthreads();
    xa1 = xa2; xb1 = xb2;
    cur ^= 1;
  }

  // ---- epilogue: lane holds D[feat = (wn*3+ct)*16+hi*4+r][token] ----
  {
    const int token = n0 + wm * 16 + c16;
    const int b = token >> 11;
    const int t = token & 2047;
#pragma unroll
    for (int ct = 0; ct < 3; ++ct) {
      int cg = (wn * 3 + ct) * 16 + hi * 4;
      unsigned short h[4];
#pragma unroll
      for (int r = 0; r < 4; ++r) h[r] = f2bf(acc[ct][r]);
      if (cg < 64) {
        *reinterpret_cast<ushort4*>(qws + (size_t)token * DDIM + cg) =
            make_ushort4(h[0], h[1], h[2], h[3]);
      } else if (cg < 128) {
        *reinterpret_cast<ushort4*>(kws + (size_t)token * DDIM + (cg - 64)) =
            make_ushort4(h[0], h[1], h[2], h[3]);
      } else {
        int cv = cg - 128;
#pragma unroll
        for (int r = 0; r < 4; ++r)
          vtws[(size_t)(b * DDIM + cv + r) * SEQ + t] = h[r];
      }
    }
  }
}

// ---------------------------------------------------------------------------
// Kernel 2: split-K flash attention partials, swapped-QK^T, K/V LDS dbuf.
//   Grid (32 qtiles, MAXCH chunks, B); 256 thr = 4 waves; wave = 16 q rows.
//   Lane owns q = qr0 + (lane&15); m/l state lane-local.
// ---------------------------------------------------------------------------
__global__ __launch_bounds__(256) void attn_partial(const unsigned short* __restrict__ qws,
                                                    const unsigned short* __restrict__ kws,
                                                    const unsigned short* __restrict__ vtws,
                                                    float* __restrict__ po,
                                                    float* __restrict__ pml,
                                                    int MAXCH, int CHUNK) {
  __shared__ __align__(16) unsigned short kt[2][64 * 64];   // K tile  [kv][d]
  __shared__ __align__(16) unsigned short vt[2][64 * 64];   // V^T tile [dv][kv]
  __shared__ unsigned short pt[4][64 * 26];                 // P^T per wave

  const int qt = blockIdx.x;
  const int ch = blockIdx.y;
  const int b  = blockIdx.z;

  const int kv_end = qt * 64 + 64;
  const int kv0_ch = ch * CHUNK;
  if (kv0_ch >= kv_end) return;
  const int block_lim = min(kv0_ch + CHUNK, kv_end);
  const int nt = (block_lim - kv0_ch + 63) >> 6;

  const int tid  = threadIdx.x;
  const int lane = tid & 63;
  const int w    = tid >> 6;
  const int c    = lane & 15;
  const int hi   = lane >> 4;
  const int qr0  = qt * 64 + w * 16;
  const int q    = qr0 + c;            // this lane's q row
  const int kv_last = qr0 + 15;        // wave causal limit

  const unsigned short* qb = qws + (size_t)b * SEQ * DDIM;
  short8 aq0 = *reinterpret_cast<const short8*>(qb + (size_t)q * DDIM + hi * 8);
  short8 aq1 = *reinterpret_cast<const short8*>(qb + (size_t)q * DDIM + 32 + hi * 8);

  float m = -INFINITY, l = 0.f;
  f32x4 o[4];
#pragma unroll
  for (int dn = 0; dn < 4; ++dn) o[dn] = (f32x4){0.f, 0.f, 0.f, 0.f};

  unsigned short* pw = pt[w];
  const unsigned short* kb = kws + (size_t)b * SEQ * DDIM;
  const unsigned short* vb = vtws + (size_t)b * DDIM * SEQ;

  // per-lane staging geometry (wave stages 128 chunk-pairs of 16B)
  auto stage_kv = [&](int bufi, int kv0) {
#pragma unroll
    for (int j = 0; j < 2; ++j) {
      int p   = w * 128 + j * 64 + lane;   // 16B chunk index 0..511
      int row = p >> 3;
      int chk = (p & 7) ^ (row & 7);
      __builtin_amdgcn_global_load_lds(
          (const __attribute__((address_space(1))) void*)(kb + (size_t)(kv0 + row) * DDIM + chk * 8),
          (__attribute__((address_space(3))) void*)(&kt[bufi][w * 1024 + j * 512]), 16, 0, 0);
      __builtin_amdgcn_global_load_lds(
          (const __attribute__((address_space(1))) void*)(vb + (size_t)row * SEQ + kv0 + chk * 8),
          (__attribute__((address_space(3))) void*)(&vt[bufi][w * 1024 + j * 512]), 16, 0, 0);
    }
  };

  stage_kv(0, kv0_ch);
  __syncthreads();

  int cur = 0;
  for (int t = 0; t < nt; ++t) {
    const int kv0 = kv0_ch + t * 64;
    if (t + 1 < nt) stage_kv(cur ^ 1, kv0 + 64);

    if (kv0 <= kv_last) {
      // ---- S^T = K q^T : lane holds S^T[kv = n*16+hi*4+r][q=c] ----
      f32x4 s[4];
#pragma unroll
      for (int n = 0; n < 4; ++n) {
        if (kv0 + n * 16 > kv_last) {
          s[n] = (f32x4){-INFINITY, -INFINITY, -INFINITY, -INFINITY};
          continue;
        }
        const unsigned short* kr = &kt[cur][(n * 16 + c) * 64];
        short8 ka0 = *reinterpret_cast<const short8*>(kr + ((hi ^ (c & 7)) * 8));
        short8 ka1 = *reinterpret_cast<const short8*>(kr + (((4 + hi) ^ (c & 7)) * 8));
        f32x4 z = (f32x4){0.f, 0.f, 0.f, 0.f};
        z = MFMA16(ka0, aq0, z);
        s[n] = MFMA16(ka1, aq1, z);
      }

      // ---- causal mask (near diagonal only) ----
      if (kv0 + 63 > qr0) {
#pragma unroll
        for (int n = 0; n < 4; ++n)
#pragma unroll
          for (int r = 0; r < 4; ++r)
            if (kv0 + n * 16 + hi * 4 + r > q) s[n][r] = -INFINITY;
      }

      // ---- online softmax (exp2 domain; state lane-local) ----
      float mx = -INFINITY;
#pragma unroll
      for (int n = 0; n < 4; ++n)
        mx = fmaxf(mx, fmaxf(fmaxf(s[n][0], s[n][1]), fmaxf(s[n][2], s[n][3])));
      mx = fmaxf(mx, __shfl_xor(mx, 16, 64));
      mx = fmaxf(mx, __shfl_xor(mx, 32, 64));

      float nm = fmaxf(m, mx);
      float sc = __builtin_exp2f(m - nm);
      m = nm;

      float ssum = 0.f;
#pragma unroll
      for (int n = 0; n < 4; ++n)
#pragma unroll
        for (int r = 0; r < 4; ++r) {
          float pv = __builtin_exp2f(s[n][r] - nm);
          pw[(n * 16 + hi * 4 + r) * 26 + c] = f2bf(pv);
          ssum += pv;
        }
      ssum += __shfl_xor(ssum, 16, 64);
      ssum += __shfl_xor(ssum, 32, 64);
      l = l * sc + ssum;

#pragma unroll
      for (int dn = 0; dn < 4; ++dn) o[dn] *= sc;

      // ---- O^T += V^T P^T ----
      const int nf = (kv0 + 32 <= kv_last) ? 2 : 1;
      for (int f = 0; f < nf; ++f) {
        short8 bp;
#pragma unroll
        for (int j = 0; j < 8; ++j)
          bp[j] = (short)pw[(f * 32 + hi * 8 + j) * 26 + c];
#pragma unroll
        for (int dn = 0; dn < 4; ++dn) {
          const unsigned short* vr = &vt[cur][(dn * 16 + c) * 64];
          short8 va = *reinterpret_cast<const short8*>(vr + (((f * 4 + hi) ^ (c & 7)) * 8));
          o[dn] = MFMA16(va, bp, o[dn]);
        }
      }
    }

    __syncthreads();   // drains next-tile stage (vmcnt) + protects cur flip
    cur ^= 1;
  }

  // ---- write partials: po [q-in-tile][dv], lane holds dv=dn*16+hi*4+r ----
  float* pob = po + (((size_t)(b * 32 + qt) * MAXCH + ch) * 64 + w * 16 + c) * 64 + hi * 4;
#pragma unroll
  for (int dn = 0; dn < 4; ++dn)
    *reinterpret_cast<f32x4*>(pob + dn * 16) = o[dn];

  if (hi == 0) {
    *reinterpret_cast<float2*>(
        pml + (((size_t)(b * 32 + qt) * MAXCH + ch) * 64 + w * 16 + c) * 2) =
        make_float2(m, l);
  }
}

// ---------------------------------------------------------------------------
// Kernel 3: combine partials.  Grid (32, B), 256 thr; thread = 1 row x 16 col
// ---------------------------------------------------------------------------
__global__ __launch_bounds__(256) void attn_combine(const float* __restrict__ po,
                                                    const float* __restrict__ pml,
                                                    float* __restrict__ out,
                                                    int MAXCH, int CHUNK) {
  const int qt = blockIdx.x;
  const int b  = blockIdx.y;
  const int tid = threadIdx.x;
  const int row = tid >> 2;
  const int cg  = tid & 3;
  const int nch = (qt * 64 + 64 + CHUNK - 1) / CHUNK;

  const size_t base = (size_t)(b * 32 + qt) * MAXCH;

  float M = -INFINITY;
  for (int ch = 0; ch < nch; ++ch)
    M = fmaxf(M, pml[(base + ch) * 128 + row * 2]);

  float L = 0.f;
  f32x4 a0 = {0.f,0.f,0.f,0.f}, a1 = a0, a2 = a0, a3 = a0;
  for (int ch = 0; ch < nch; ++ch) {
    float mv = pml[(base + ch) * 128 + row * 2];
    float lv = pml[(base + ch) * 128 + row * 2 + 1];
    float wgt = __builtin_exp2f(mv - M);
    L += wgt * lv;
    const float* p = po + (base + ch) * 4096 + row * 64 + cg * 16;
    a0 += wgt * *reinterpret_cast<const f32x4*>(p);
    a1 += wgt * *reinterpret_cast<const f32x4*>(p + 4);
    a2 += wgt * *reinterpret_cast<const f32x4*>(p + 8);
    a3 += wgt * *reinterpret_cast<const f32x4*>(p + 12);
  }
  float invL = 1.f / L;
  float* ob = out + ((size_t)b * SEQ + qt * 64 + row) * 64 + cg * 16;
  *reinterpret_cast<f32x4*>(ob)      = a0 * invL;
  *reinterpret_cast<f32x4*>(ob + 4)  = a1 * invL;
  *reinterpret_cast<f32x4*>(ob + 8)  = a2 * invL;
  *reinterpret_cast<f32x4*>(ob + 12) = a3 * invL;
}

// ---------------------------------------------------------------------------
extern "C" void kernel_launch(void* const* d_in, const int* in_sizes, int n_in,
                              void* d_out, int out_size, void* d_ws, size_t ws_size,
                              hipStream_t stream) {
  const float* x  = (const float*)d_in[0];
  const float* Wq = (const float*)d_in[1];
  const float* Wk = (const float*)d_in[2];
  const float* Wv = (const float*)d_in[3];
  float* out = (float*)d_out;

  unsigned short* qws  = (unsigned short*)d_ws;            // 2MB
  unsigned short* kws  = qws + (size_t)NTOK * DDIM;        // 2MB
  unsigned short* vtws = kws + (size_t)NTOK * DDIM;        // 2MB
  unsigned short* WT   = vtws + (size_t)NTOK * DDIM;       // 384KB
  size_t fixed_end = (size_t)NTOK * DDIM * 3 * 2 + 192 * 1024 * 2;

  int MAXCH = 1;
  {
    const int cand[4] = {8, 4, 2, 1};
    for (int i = 0; i < 4; ++i) {
      size_t need = fixed_end +
                    (size_t)cand[i] * (8ull * 32 * 64 * 64 * 4 + 8ull * 32 * 64 * 2 * 4);
      if (need <= ws_size) { MAXCH = cand[i]; break; }
    }
  }

  wt_kernel<<<768, 256, 0, stream>>>(Wq, Wk, Wv, WT);
  proj_kernel<<<NTOK / 32, 512, 0, stream>>>(x, WT, qws, kws, vtws);

  float* po  = (float*)((char*)d_ws + fixed_end);
  float* pml = po + (size_t)BATCH * 32 * MAXCH * 64 * 64;
  int CHUNK = SEQ / MAXCH;
  attn_partial<<<dim3(32, MAXCH, BATCH), 256, 0, stream>>>(qws, kws, vtws, po, pml,
                                                           MAXCH, CHUNK);
  attn_combine<<<dim3(32, BATCH), 256, 0, stream>>>(po, pml, out, MAXCH, CHUNK);
}